// Round 11
// baseline (138.997 us; speedup 1.0000x reference)
//
#include <hip/hip_runtime.h>

// Problem constants (N=1, C=64, H=W=80)
#define LDIM 6400
#define CDIM 64
#define WDIM 80
#define NEGV -1e9f

// Orderable (ascending) encoding of fp32.
__device__ __forceinline__ unsigned encf(float f) {
    unsigned b = __float_as_uint(f);
    return (b & 0x80000000u) ? ~b : (b | 0x80000000u);
}
__device__ __forceinline__ float decf(unsigned e) {
    unsigned b = (e & 0x80000000u) ? (e ^ 0x80000000u) : ~e;
    return __uint_as_float(b);
}

// init: zero rowp/colenc + write data-independent mkpts0 (25 blocks, ~2 us)
__global__ void init_kernel(unsigned long long* __restrict__ rowp,
                            unsigned* __restrict__ colenc,
                            float* __restrict__ out) {
    int i = blockIdx.x * 256 + threadIdx.x;
    if (i < LDIM) {
        rowp[i] = 0ull;
        colenc[i] = 0u;
        out[2 * i]     = (float)((i % WDIM) * 8);
        out[2 * i + 1] = (float)((i / WDIM) * 8);
    }
}

// main: blocks [0,5000) = conf tiles of 32 rows x 256 cols; 4 waves/block,
// each wave owns 8 WAVE-UNIFORM rows (A-fragment via s_load through the
// constant cache -- off the LDS pipe, which was the 50us limiter per R10's
// post-mortem: 4 ds_read_b128/wave/c-step = 2.56M x 12cyc/256CU vs 33us FMA)
// x 64 lanes x 4 cols. B staged in LDS (16ch slab x 256 cols = exactly
// 16384 B), one ds_read_b128 per lane per c-step (consecutive-float4
// pattern, conflict-free). v_fma_f32 takes A as its one SGPR operand.
// blocks [5000,6600) = bilinear upsample (backfills the tail).
// __launch_bounds__(256,4): VGPR cap 128, allocator not squeezed (R3:
// tight cap -> accumulator spill -> 544 MB scratch, 2.8x regression).
__global__ __launch_bounds__(256, 4) void main_kernel(
        const float* __restrict__ A, const float* __restrict__ B,
        const float* __restrict__ sav, const float* __restrict__ sai,
        unsigned long long* __restrict__ rowp, unsigned* __restrict__ colenc,
        float* __restrict__ out) {
    __shared__ float smem[4096];    // 16 KB: B-slab / epilogue col-scratch
    const int tid = threadIdx.x;
    const int b = blockIdx.x;

    if (b >= 5000) {
        // ---- upsample path ----
        int i = (b - 5000) * 256 + tid;   // < 640*640
        int oy = i / 640, ox = i % 640;
        const float step = 79.0f / 639.0f;
        float fy = (float)oy * step;
        float fx = (float)ox * step;
        int y0 = (int)floorf(fy); if (y0 > 79) y0 = 79; if (y0 < 0) y0 = 0;
        int x0 = (int)floorf(fx); if (x0 > 79) x0 = 79; if (x0 < 0) x0 = 0;
        int y1 = (y0 + 1 < 80) ? y0 + 1 : 79;
        int x1 = (x0 + 1 < 80) ? x0 + 1 : 79;
        float wy = fy - (float)y0;
        float wx = fx - (float)x0;
        float v00 = sai[y0 * 80 + x0], v01 = sai[y0 * 80 + x1];
        float v10 = sai[y1 * 80 + x0], v11 = sai[y1 * 80 + x1];
        float r0 = v00 * (1.0f - wy) + v10 * wy;
        float r1 = v01 * (1.0f - wy) + v11 * wy;
        out[38400 + i] = r0 * (1.0f - wx) + r1 * wx;
        return;
    }

    // ---- conf tile path: 32 rows x 256 cols ----
    const int lb = (b / 25) * 32;    // row (vi) base
    const int sb = (b % 25) * 256;   // col (ir) base
    const int lane = tid & 63;
    // wave id, forced wave-uniform so A addressing scalarizes to s_load
    const int wv = __builtin_amdgcn_readfirstlane(tid >> 6);   // 0..3
    const int r0 = lb + 8 * wv;

    float acc[8][4];
    #pragma unroll
    for (int i = 0; i < 8; ++i)
        #pragma unroll
        for (int j = 0; j < 4; ++j) acc[i][j] = 0.0f;

    float4* Bs4 = (float4*)smem;
    const float4* pB = (const float4*)smem;

    for (int kb = 0; kb < 4; ++kb) {
        // stage B slab: 16 ch x 256 cols (1024 float4, 4 per thread)
        #pragma unroll
        for (int it = 0; it < 4; ++it) {
            int i = tid + it * 256;
            int c = i >> 6, q = i & 63;
            Bs4[i] = ((const float4*)(B + (kb * 16 + c) * LDIM + sb))[q];
        }
        __syncthreads();

        #pragma unroll 4
        for (int c = 0; c < 16; ++c) {
            float4 bq = pB[(c << 6) + lane];          // one b128, conflict-free
            const float* aw = A + (kb * 16 + c) * LDIM + r0;  // wave-uniform
            float bv[4] = {bq.x, bq.y, bq.z, bq.w};
            #pragma unroll
            for (int i = 0; i < 8; ++i) {
                float a = aw[i];                       // s_load (SGPR operand)
                #pragma unroll
                for (int j = 0; j < 4; ++j)
                    acc[i][j] = fmaf(a, bv[j], acc[i][j]);
            }
        }
        __syncthreads();   // drain reads before next slab overwrite / epilogue
    }

    bool rok[8], cok[4];
    #pragma unroll
    for (int i = 0; i < 8; ++i) rok[i] = sav[r0 + i] > 0.0f;   // scalar
    #pragma unroll
    for (int j = 0; j < 4; ++j) cok[j] = sai[sb + lane * 4 + j] > 0.0f;

    float conf[8][4];
    #pragma unroll
    for (int i = 0; i < 8; ++i)
        #pragma unroll
        for (int j = 0; j < 4; ++j)
            conf[i][j] = (rok[i] && cok[j]) ? acc[i][j] * 0.15625f : NEGV;

    // ---- row reduction across the full wave (64 lanes = 256 cols) ----
    #pragma unroll
    for (int i = 0; i < 8; ++i) {
        float v = conf[i][0];
        int ci = sb + lane * 4;
        #pragma unroll
        for (int j = 1; j < 4; ++j) {      // strict > keeps earliest index
            bool up = conf[i][j] > v;
            v = up ? conf[i][j] : v;
            ci = up ? sb + lane * 4 + j : ci;
        }
        #pragma unroll
        for (int d = 1; d < 64; d <<= 1) { // 64-lane butterfly
            float ov = __shfl_xor(v, d, 64);
            int oi = __shfl_xor(ci, d, 64);
            bool take = (ov > v) || ((ov == v) && (oi < ci));
            v = take ? ov : v;
            ci = take ? oi : ci;
        }
        if (lane == 0)
            atomicMax(&rowp[r0 + i],
                      ((unsigned long long)encf(v) << 32) |
                      (unsigned)(~(unsigned)ci));
    }

    // ---- col reduction via LDS (reuse smem; [wave][col] = 1024 floats) ----
    // (safe: last K-iter ended with __syncthreads; no Bs reads since)
    float cm0[4];
    #pragma unroll
    for (int j = 0; j < 4; ++j) {
        float m = conf[0][j];
        #pragma unroll
        for (int i = 1; i < 8; ++i) m = fmaxf(m, conf[i][j]);
        cm0[j] = m;
    }
    *(float4*)&smem[wv * 1024 + lane * 4] =
        make_float4(cm0[0], cm0[1], cm0[2], cm0[3]);
    __syncthreads();
    {
        float m = fmaxf(fmaxf(smem[tid], smem[1024 + tid]),
                        fmaxf(smem[2048 + tid], smem[3072 + tid]));
        atomicMax(&colenc[sb + tid], encf(m));
    }
}

// finalize: mutual-NN check + write mkpts1/mask_v/score (25 blocks, ~2 us)
__global__ void finalize_kernel(const unsigned long long* __restrict__ rowp,
                                const unsigned* __restrict__ colenc,
                                float* __restrict__ out) {
    int l = blockIdx.x * 256 + threadIdx.x;
    if (l >= LDIM) return;
    unsigned long long p = rowp[l];
    unsigned enc = (unsigned)(p >> 32);
    unsigned s = ~((unsigned)p);          // row argmax column (first on ties)
    float val = decf(enc);
    bool mk = (enc == colenc[s]) && (val > 0.0f);
    int aj = mk ? (int)s : 0;             // argmax(mask) == 0 when mask row empty
    out[12800 + 2 * l]     = (float)((aj % WDIM) * 8);
    out[12800 + 2 * l + 1] = (float)((aj / WDIM) * 8);
    out[25600 + l] = mk ? 1.0f : 0.0f;
    out[32000 + l] = mk ? val : 0.0f;
}

extern "C" void kernel_launch(void* const* d_in, const int* in_sizes, int n_in,
                              void* d_out, int out_size, void* d_ws, size_t ws_size,
                              hipStream_t stream) {
    const float* frv = (const float*)d_in[0];  // feat_reg_vi [64,6400]
    const float* fri = (const float*)d_in[1];  // feat_reg_ir [64,6400]
    const float* sav = (const float*)d_in[2];  // feat_sa_vi  [6400]
    const float* sai = (const float*)d_in[3];  // feat_sa_ir  [6400]
    float* out = (float*)d_out;

    unsigned long long* rowp = (unsigned long long*)d_ws;
    unsigned* colenc = (unsigned*)((char*)d_ws + LDIM * sizeof(unsigned long long));

    init_kernel<<<25, 256, 0, stream>>>(rowp, colenc, out);
    main_kernel<<<6600, 256, 0, stream>>>(frv, fri, sav, sai, rowp, colenc, out);
    finalize_kernel<<<25, 256, 0, stream>>>(rowp, colenc, out);
}